// Round 3
// baseline (408.067 us; speedup 1.0000x reference)
//
#include <hip/hip_runtime.h>

#define DEVI __device__ __forceinline__

constexpr float SCALE = 0.0625f;   // 256^-0.5
constexpr float LN_EPS = 1e-5f;

DEVI float dot8f(const float* __restrict__ w, const float* __restrict__ x){
  float4 a = *(const float4*)w;
  float4 b = *(const float4*)(w + 4);
  return a.x*x[0]+a.y*x[1]+a.z*x[2]+a.w*x[3]+b.x*x[4]+b.y*x[5]+b.z*x[6]+b.w*x[7];
}

// 256-thr 256x256 GEMV (proven): out[tid] = dot(W[tid][:], xv[:]).
// Caller must have xv synced. Ends with the part-reduce; caller must sync
// before re-writing xv or part.
DEVI float gemv256(const float* __restrict__ W, const float* __restrict__ xv,
                   float (*part)[33], int tid){
  const int c8 = tid & 31, ep = tid >> 5;
  float xs8[8];
  #pragma unroll
  for (int j = 0; j < 8; ++j) xs8[j] = xv[c8*8 + j];
  const float* Wb = W + c8*8;
  #pragma unroll 4
  for (int ei = 0; ei < 32; ++ei){
    int e = ep*32 + ei;
    part[e][c8] = dot8f(Wb + (size_t)e*256, xs8);
  }
  __syncthreads();
  float acc = 0.f;
  #pragma unroll
  for (int p = 0; p < 32; ++p) acc += part[tid][p];
  return acc;
}

// LayerNorm over the 256 values held one-per-thread (proven).
DEVI float block_ln(float x, const float* __restrict__ g, const float* __restrict__ be,
                    float* red, int tid, int lane, int wv){
  float v1 = x, v2 = x*x;
  #pragma unroll
  for (int o = 32; o; o >>= 1){ v1 += __shfl_xor(v1,o,64); v2 += __shfl_xor(v2,o,64); }
  if (lane == 0){ red[wv] = v1; red[4+wv] = v2; }
  __syncthreads();
  float mu = (red[0]+red[1]+red[2]+red[3]) * (1.f/256.f);
  float var = (red[4]+red[5]+red[6]+red[7]) * (1.f/256.f) - mu*mu;
  float inv = rsqrtf(var + LN_EPS);
  float r = (x - mu)*inv*g[tid] + be[tid];
  __syncthreads();
  return r;
}

// q-projection chain for one row: LN_s(slot) -> Wq -> Wk[s]^T -> qg, gqbq.
// Identical math/order to the proven kS5+kS6 pair.
DEVI void qproj(float sval, int r, int s, int tid,
                const float* __restrict__ g_s, const float* __restrict__ be_s,
                const float* __restrict__ Wq, const float* __restrict__ Wk,
                const float* __restrict__ g_in, const float* __restrict__ be_in,
                float* __restrict__ qg, float* __restrict__ gqbq,
                float* xv, float (*part)[33], float* red){
  const int lane = tid & 63, wv = tid >> 6;
  float sn = block_ln(sval, g_s, be_s, red, tid, lane, wv);  // internal syncs
  xv[tid] = sn;
  __syncthreads();
  float q = gemv256(Wq, xv, part, tid);
  __syncthreads();                       // part reads done
  xv[tid] = q;
  __syncthreads();
  // qk[c] = sum_e q[e] * Wk[s][e][c]   (kS6 pattern; partK aliased onto part)
  float* partK = &part[0][0];            // uses [0 .. 2048) of the 8448-float buffer
  const int c8 = tid & 31, ep = tid >> 5;
  float acc8[8];
  #pragma unroll
  for (int j = 0; j < 8; ++j) acc8[j] = 0.f;
  const float* Wb = Wk + ((size_t)s*256)*256 + c8*8;
  #pragma unroll 4
  for (int ei = 0; ei < 32; ++ei){
    int e = ep*32 + ei;
    const float* wp = Wb + (size_t)e*256;
    float4 wa = *(const float4*)wp;
    float4 wb = *(const float4*)(wp + 4);
    float qe = xv[e];
    acc8[0] += qe*wa.x; acc8[1] += qe*wa.y; acc8[2] += qe*wa.z; acc8[3] += qe*wa.w;
    acc8[4] += qe*wb.x; acc8[5] += qe*wb.y; acc8[6] += qe*wb.z; acc8[7] += qe*wb.w;
  }
  float* pk = partK + ep*256 + c8*8;
  #pragma unroll
  for (int j = 0; j < 8; ++j) pk[j] = acc8[j];
  __syncthreads();
  float qk = 0.f;
  #pragma unroll
  for (int p = 0; p < 8; ++p) qk += partK[p*256 + tid];
  float qgv = qk * g_in[tid] * SCALE;
  float bqv = qk * be_in[tid] * SCALE;
  qg[r*256 + tid] = qgv;
  float vq = qgv, vb = bqv;
  #pragma unroll
  for (int o = 32; o; o >>= 1){ vq += __shfl_xor(vq,o,64); vb += __shfl_xor(vb,o,64); }
  if (lane == 0){ red[wv] = vq; red[4+wv] = vb; }
  __syncthreads();
  if (tid == 0) gqbq[r*2+0] = red[0]+red[1]+red[2]+red[3];
  if (tid == 1) gqbq[r*2+1] = red[4]+red[5]+red[6]+red[7];
}

// ---------------- kInitQ: slots init + zero accumulators + q-projection ----------------
__global__ __launch_bounds__(256) void k_initq(const float* __restrict__ noise,
    const float* __restrict__ smu, const float* __restrict__ slsig,
    float* __restrict__ slotsA, float* __restrict__ uacc, float* __restrict__ Zacc,
    const float* __restrict__ g_s, const float* __restrict__ be_s,
    const float* __restrict__ Wq, const float* __restrict__ Wk,
    const float* __restrict__ g_in, const float* __restrict__ be_in,
    float* __restrict__ qg, float* __restrict__ gqbq){
  __shared__ float xv[256];
  __shared__ float part[256][33];
  __shared__ float red[8];
  const int r = blockIdx.x, tid = threadIdx.x, s = r & 7;
  float sl = smu[s*256 + tid] + expf(slsig[s*256 + tid]) * noise[r*256 + tid];
  slotsA[r*256 + tid] = sl;
  uacc[r*256 + tid] = 0.f;
  if (tid == 0) Zacc[r] = 0.f;
  qproj(sl, r, s, tid, g_s, be_s, Wq, Wk, g_in, be_in, qg, gqbq, xv, part, red);
}

// ---------------- k_updA: upd = (uacc@Wv[s]^T)/Z ; GRU gates ; h -> hbuf ----------------
// Also re-zeroes uacc/Zacc for the next k_main.
__global__ __launch_bounds__(256) void k_updA(const float* __restrict__ sin_,
    float* __restrict__ uacc, float* __restrict__ Zacc,
    const float* __restrict__ Wv, const float* __restrict__ W_ih,
    const float* __restrict__ W_hh,
    const float* __restrict__ b_ih, const float* __restrict__ b_hh,
    float* __restrict__ hbuf){
  __shared__ float xv[256];
  __shared__ float part[256][33];
  const int r = blockIdx.x, tid = threadIdx.x, s = r & 7;

  // ---- stage 1: upd = gemv(Wv[s], uacc) / Z ; re-zero accumulators ----
  float rZ = 1.f / Zacc[r];            // load precedes gemv's internal barrier
  xv[tid] = uacc[r*256 + tid];
  uacc[r*256 + tid] = 0.f;             // same-thread element: no race
  __syncthreads();
  float upd = gemv256(Wv + (size_t)s*65536, xv, part, tid) * rZ;
  if (tid == 0) Zacc[r] = 0.f;         // all rZ loads happened before the barrier

  // ---- stage 2: gh gates from sin (xv <- sin stays for 3 gemvs) ----
  float hp = sin_[r*256 + tid];
  xv[tid] = hp;                        // xs8 reads of stage 1 precede its barrier
  __syncthreads();
  float hr_ = gemv256(W_hh,          xv, part, tid) + b_hh[tid];
  __syncthreads();
  float hz_ = gemv256(W_hh +  65536, xv, part, tid) + b_hh[256 + tid];
  __syncthreads();
  float hn_ = gemv256(W_hh + 131072, xv, part, tid) + b_hh[512 + tid];

  // ---- stage 3: gi gates from upd ----
  xv[tid] = upd;
  __syncthreads();
  float ir_ = gemv256(W_ih,          xv, part, tid) + b_ih[tid];
  __syncthreads();
  float iz_ = gemv256(W_ih +  65536, xv, part, tid) + b_ih[256 + tid];
  __syncthreads();
  float in_ = gemv256(W_ih + 131072, xv, part, tid) + b_ih[512 + tid];

  // ---- stage 4: GRU combine (identical math to proven kS3) ----
  float rg = 1.f/(1.f + expf(-(ir_ + hr_)));
  float zg = 1.f/(1.f + expf(-(iz_ + hz_)));
  float ng = tanhf(in_ + rg*hn_);
  hbuf[r*256 + tid] = (1.f - zg)*ng + zg*hp;
}

// ---------------- k_updB: LN_ff -> W1 -> relu -> W2 -> sout ; then qproj ----------------
__global__ __launch_bounds__(256) void k_updB(const float* __restrict__ hbuf,
    float* __restrict__ sout,
    const float* __restrict__ g_ff, const float* __restrict__ be_ff,
    const float* __restrict__ W1, const float* __restrict__ b1,
    const float* __restrict__ W2, const float* __restrict__ b2,
    const float* __restrict__ g_s, const float* __restrict__ be_s,
    const float* __restrict__ Wq, const float* __restrict__ Wk,
    const float* __restrict__ g_in, const float* __restrict__ be_in,
    float* __restrict__ qg, float* __restrict__ gqbq,
    float* __restrict__ out_slots, int last){
  __shared__ float xv[256];
  __shared__ float part[256][33];
  __shared__ float red[8];
  const int r = blockIdx.x, tid = threadIdx.x, s = r & 7;
  const int lane = tid & 63, wv = tid >> 6;

  float h = hbuf[r*256 + tid];
  float lnh = block_ln(h, g_ff, be_ff, red, tid, lane, wv);  // internal syncs
  xv[tid] = lnh;
  __syncthreads();
  float hid = fmaxf(gemv256(W1, xv, part, tid) + b1[tid], 0.f);
  __syncthreads();
  xv[tid] = hid;
  __syncthreads();
  float out = h + gemv256(W2, xv, part, tid) + b2[tid];
  sout[r*256 + tid] = out;
  if (last){ out_slots[r*256 + tid] = out; return; }   // 'last' is wave-uniform

  qproj(out, r, s, tid, g_s, be_s, Wq, Wk, g_in, be_in, qg, gqbq, xv, part, red);
}

// ---------------- K1: fused LN + dots + softmax(slots) + weighted-emb accumulation ------
__global__ __launch_bounds__(256) void k_main(const float* __restrict__ emb,
    const float* __restrict__ qg, const float* __restrict__ gqbq,
    const float* __restrict__ g_in, const float* __restrict__ be_in,
    float* __restrict__ uacc, float* __restrict__ Zacc,
    float* __restrict__ out_attn, int write_attn){
  __shared__ float U[8192];                    // 32 KB union
  float* const qgL = U;                        // [2048] phase 1 (bank-swizzled)
  float* const avL = U + 2048;                 // [512]  phase 1
  float4* const Sp4 = (float4*)U;              // [2048] phase 2 partials
  __shared__ float aL[512];
  __shared__ float red2[2][8][4];
  __shared__ float Zs[8], A2s[8], GqL[8], BqL[8];

  const int tid = threadIdx.x, lane = tid & 63, wv = tid >> 6;
  const int blk = blockIdx.x, b = blk >> 6, tile = blk & 63;
  const int n0 = tile * 64;

  { // stage queries with per-qq rotation so the 8 qq-chunks hit distinct banks
    const float4* src = (const float4*)(qg + (size_t)b * 2048);
    float4* dst = (float4*)qgL;
    #pragma unroll
    for (int k = 0; k < 2; ++k){
      int w = tid + k*256;                 // 0..511
      int s = w >> 6, f = w & 63, qq = f >> 3, j = f & 7;
      dst[s*64 + qq*8 + ((j + qq) & 7)] = src[w];
    }
  }
  if (tid < 8){
    GqL[tid] = gqbq[(b*8 + tid)*2 + 0];
    BqL[tid] = gqbq[(b*8 + tid)*2 + 1];
  }
  __syncthreads();

  const int qq = tid & 7;   // 32-col chunk
  float zsum[8], z2sum[8];
  #pragma unroll
  for (int s = 0; s < 8; ++s){ zsum[s] = 0.f; z2sum[s] = 0.f; }

  #pragma unroll
  for (int pass = 0; pass < 2; ++pass){
    const int t = pass*32 + (tid >> 3);   // token 0..63
    const float4* xrow = (const float4*)(emb + ((size_t)(b*4096 + n0 + t))*256 + qq*32);
    float4 xv4[8];
    #pragma unroll
    for (int j = 0; j < 8; ++j) xv4[j] = xrow[j];
    float s1 = 0.f, s2 = 0.f, acc[8];
    #pragma unroll
    for (int s = 0; s < 8; ++s) acc[s] = 0.f;
    #pragma unroll
    for (int j = 0; j < 8; ++j){
      float4 u = xv4[j];
      s1 += (u.x+u.y)+(u.z+u.w);
      s2 += u.x*u.x+u.y*u.y+u.z*u.z+u.w*u.w;
      const float* qb = qgL + qq*32 + ((j + qq) & 7)*4;
      #pragma unroll
      for (int s = 0; s < 8; ++s){
        float4 q0 = *(const float4*)(qb + s*256);
        acc[s] += u.x*q0.x + u.y*q0.y + u.z*q0.z + u.w*q0.w;
      }
    }
    #pragma unroll
    for (int o = 1; o <= 4; o <<= 1){
      s1 += __shfl_xor(s1,o,64); s2 += __shfl_xor(s2,o,64);
      #pragma unroll
      for (int s = 0; s < 8; ++s) acc[s] += __shfl_xor(acc[s],o,64);
    }
    float mu = s1 * (1.f/256.f);
    float var = s2 * (1.f/256.f) - mu*mu;
    float inv = rsqrtf(var + LN_EPS);
    float dv[8], mx = -1e30f;
    #pragma unroll
    for (int s = 0; s < 8; ++s){
      dv[s] = inv * (acc[s] - mu * GqL[s]) + BqL[s];
      mx = fmaxf(mx, dv[s]);
    }
    float den = 0.f;
    #pragma unroll
    for (int s = 0; s < 8; ++s){ dv[s] = expf(dv[s] - mx); den += dv[s]; }
    float rden = 1.f / den;
    #pragma unroll
    for (int s = 0; s < 8; ++s){
      float at = dv[s] * rden;       // attn (softmax over slots)
      float av = at * inv;           // attn * inv (LN folded)
      if (qq == 0){ avL[s*64 + t] = at; aL[s*64 + t] = av; }
      zsum[s] += at;                 // deferred reduction (single butterfly below)
      z2sum[s] += av * mu;
    }
  }
  // one butterfly for Z/A2 instead of per-pass (each token counted by 8 lanes)
  #pragma unroll
  for (int s = 0; s < 8; ++s){
    #pragma unroll
    for (int o = 32; o; o >>= 1){
      zsum[s] += __shfl_xor(zsum[s], o, 64);
      z2sum[s] += __shfl_xor(z2sum[s], o, 64);
    }
  }
  if (lane == 0){
    #pragma unroll
    for (int s = 0; s < 8; ++s){ red2[0][s][wv] = zsum[s]*0.125f; red2[1][s][wv] = z2sum[s]*0.125f; }
  }
  __syncthreads();
  if (tid < 8){
    Zs[tid]  = red2[0][tid][0]+red2[0][tid][1]+red2[0][tid][2]+red2[0][tid][3];
    A2s[tid] = red2[1][tid][0]+red2[1][tid][1]+red2[1][tid][2]+red2[1][tid][3];
  }
  if (write_attn){
    int s = tid >> 5, tk = tid & 31;
    #pragma unroll
    for (int p = 0; p < 2; ++p)
      out_attn[((size_t)(b*8 + s))*4096 + n0 + p*32 + tk] = avL[s*64 + p*32 + tk];
  }
  __syncthreads();                   // avL/qgL dead past here; Sp4 takes over U
  { // phase 2: coalesced f4 token-weighted accumulation
    const int r4 = tid >> 6, cq = tid & 63;
    float4 S1[8];
    #pragma unroll
    for (int s = 0; s < 8; ++s) S1[s] = make_float4(0.f,0.f,0.f,0.f);
    const float4* xbase = (const float4*)(emb + ((size_t)(b*4096 + n0))*256) + cq;
    #pragma unroll 4
    for (int i = 0; i < 16; ++i){
      int t = r4 + i*4;
      float4 x4 = xbase[t*64];
      #pragma unroll
      for (int s = 0; s < 8; ++s){
        float a = aL[s*64 + t];   // wave-uniform broadcast
        S1[s].x += a*x4.x; S1[s].y += a*x4.y; S1[s].z += a*x4.z; S1[s].w += a*x4.w;
      }
    }
    #pragma unroll
    for (int s = 0; s < 8; ++s) Sp4[(r4*8 + s)*64 + cq] = S1[s];
  }
  __syncthreads();
  { // final: sum 4 wave-partials per (s,c), atomically accumulate (s staggered)
    const int c = tid;
    const float* Sp = (const float*)Sp4;
    float gc = g_in[c], bc = be_in[c];
    float* dst = uacc + ((size_t)b*8)*256 + c;
    #pragma unroll
    for (int si = 0; si < 8; ++si){
      int s = (si + blk) & 7;
      float v = Sp[(0*8+s)*256 + c] + Sp[(1*8+s)*256 + c]
              + Sp[(2*8+s)*256 + c] + Sp[(3*8+s)*256 + c];
      atomicAdd(&dst[s*256], gc * (v - A2s[s]) + bc * Zs[s]);
    }
    if (tid < 8) atomicAdd(&Zacc[b*8 + tid], Zs[tid]);
  }
}

extern "C" void kernel_launch(void* const* d_in, const int* in_sizes, int n_in,
                              void* d_out, int out_size, void* d_ws, size_t ws_size,
                              hipStream_t stream){
  const float* emb   = (const float*)d_in[0];
  const float* noise = (const float*)d_in[1];
  const float* smu   = (const float*)d_in[2];
  const float* slsig = (const float*)d_in[3];
  const float* Wk    = (const float*)d_in[4];
  const float* Wq    = (const float*)d_in[5];
  const float* Wv    = (const float*)d_in[6];
  const float* W_ih  = (const float*)d_in[7];
  const float* W_hh  = (const float*)d_in[8];
  const float* b_ih  = (const float*)d_in[9];
  const float* b_hh  = (const float*)d_in[10];
  const float* W1    = (const float*)d_in[11];
  const float* b1    = (const float*)d_in[12];
  const float* W2    = (const float*)d_in[13];
  const float* b2    = (const float*)d_in[14];
  const float* g_in  = (const float*)d_in[15];
  const float* be_in = (const float*)d_in[16];
  const float* g_s   = (const float*)d_in[17];
  const float* be_s  = (const float*)d_in[18];
  const float* g_ff  = (const float*)d_in[19];
  const float* be_ff = (const float*)d_in[20];

  float* ws     = (float*)d_ws;
  float* slotsA = ws;                 // 32768
  float* slotsB = ws + 32768;         // 32768
  float* qg     = ws + 65536;         // 32768
  float* gqbq   = ws + 98304;         // 256
  float* uacc   = ws + 98560;         // 32768
  float* Zacc   = ws + 131328;        // 128
  float* hbuf   = ws + 131456;        // 32768

  float* out_slots = (float*)d_out;
  float* out_attn  = out_slots + 32768;
  const int has_attn = (out_size >= 32768 + 16*8*4096);

  k_initq<<<dim3(128), dim3(256), 0, stream>>>(noise, smu, slsig, slotsA, uacc, Zacc,
      g_s, be_s, Wq, Wk, g_in, be_in, qg, gqbq);
  for (int it = 0; it < 3; ++it){
    int last = (it == 2);
    float* sin  = (it == 1) ? slotsB : slotsA;
    float* sout = (it == 1) ? slotsA : slotsB;
    k_main<<<dim3(1024), dim3(256), 0, stream>>>(emb, qg, gqbq, g_in, be_in,
        uacc, Zacc, out_attn, last && has_attn);
    k_updA<<<dim3(128), dim3(256), 0, stream>>>(sin, uacc, Zacc,
        Wv, W_ih, W_hh, b_ih, b_hh, hbuf);
    k_updB<<<dim3(128), dim3(256), 0, stream>>>(hbuf, sout,
        g_ff, be_ff, W1, b1, W2, b2,
        g_s, be_s, Wq, Wk, g_in, be_in, qg, gqbq, out_slots, last);
  }
}